// Round 1
// 919.616 us; speedup vs baseline: 1.2785x; 1.2785x over previous
//
#include <hip/hip_runtime.h>
#include <math.h>

#define Nn 12288
#define Ee 393216
#define INF 256
#define Hh 128
#define DZ 64

// ---------------- degree + norm ----------------
__global__ void deg_kernel(const int* __restrict__ dst, float* __restrict__ deg) {
    int i = blockIdx.x * 256 + threadIdx.x;
    if (i < Ee) atomicAdd(&deg[dst[i]], 1.0f);
}

__global__ void norm_kernel(const float* __restrict__ deg, float* __restrict__ nrm) {
    int i = blockIdx.x * 256 + threadIdx.x;
    if (i < Nn) nrm[i] = 1.0f / sqrtf(fmaxf(deg[i], 1.0f));
}

// ---------------- exclusive scan of degrees -> CSR row offsets (N = 1024*12) ----------------
__global__ __launch_bounds__(1024) void scan_kernel(const float* __restrict__ deg,
                                                    int* __restrict__ offs,
                                                    int* __restrict__ cursor) {
    __shared__ int part[1024];
    int t = threadIdx.x;
    int base = t * 12;
    int loc[12];
    int s = 0;
#pragma unroll
    for (int k = 0; k < 12; ++k) { loc[k] = s; s += (int)deg[base + k]; }
    part[t] = s;
    __syncthreads();
    // Hillis-Steele inclusive scan over 1024 partials
    for (int off = 1; off < 1024; off <<= 1) {
        int v = (t >= off) ? part[t - off] : 0;
        __syncthreads();
        part[t] += v;
        __syncthreads();
    }
    int pre = (t == 0) ? 0 : part[t - 1];
#pragma unroll
    for (int k = 0; k < 12; ++k) {
        int o = pre + loc[k];
        offs[base + k] = o;
        cursor[base + k] = o;
    }
    if (t == 1023) offs[Nn] = part[1023];
}

// ---------------- counting-sort edges by dst: csr_src[p] = src ----------------
__global__ void csr_kernel(const int* __restrict__ src, const int* __restrict__ dst,
                           int* __restrict__ cursor, int* __restrict__ csr_src) {
    int e = blockIdx.x * 256 + threadIdx.x;
    if (e < Ee) {
        int p = atomicAdd(&cursor[dst[e]], 1);
        csr_src[p] = src[e];
    }
}

// ---------------- layer1 GEMM: tmp1 = (X @ W0) * norm  [N,128] ----------------
__global__ __launch_bounds__(128) void gemm1_kernel(const float* __restrict__ X,
                                                    const float* __restrict__ W0,
                                                    const float* __restrict__ nrm,
                                                    float* __restrict__ out) {
    __shared__ float xs[16][INF];  // 16 rows x 256 = 16 KB
    int r0 = blockIdx.x * 16;
    int tid = threadIdx.x;
    const float4* X4 = (const float4*)(X + (size_t)r0 * INF);
    float4* xs4 = (float4*)&xs[0][0];
    for (int idx = tid; idx < 16 * INF / 4; idx += 128) xs4[idx] = X4[idx];
    __syncthreads();
    int j = tid;  // 0..127 output column
    float acc[16];
#pragma unroll
    for (int r = 0; r < 16; ++r) acc[r] = 0.0f;
    for (int k = 0; k < INF; ++k) {
        float w = W0[k * Hh + j];
#pragma unroll
        for (int r = 0; r < 16; ++r) acc[r] += xs[r][k] * w;
    }
#pragma unroll
    for (int r = 0; r < 16; ++r) out[(size_t)(r0 + r) * Hh + j] = acc[r] * nrm[r0 + r];
}

// ---------------- agg1: gather-sum over CSR (one node per block, 128 feats) ----------------
__global__ __launch_bounds__(128) void agg1_kernel(const int* __restrict__ csr_src,
                                                   const int* __restrict__ offs,
                                                   const float* __restrict__ tmp1,
                                                   float* __restrict__ agg1) {
    __shared__ int sidx[128];
    int node = blockIdx.x;
    int beg = offs[node], end = offs[node + 1];
    int f = threadIdx.x;
    float acc = 0.0f;
    for (int e0 = beg; e0 < end; e0 += 128) {
        int n = min(128, end - e0);
        if (f < n) sidx[f] = csr_src[e0 + f];
        __syncthreads();
        for (int t = 0; t < n; ++t)
            acc += tmp1[(size_t)sidx[t] * Hh + f];
        __syncthreads();
    }
    agg1[(size_t)node * Hh + f] = acc;
}

// ---------------- layer2 GEMMs (fused m & s): tmp = ((agg1*norm) @ W) * norm ----------------
__global__ __launch_bounds__(128) void gemm2_kernel(const float* __restrict__ agg1,
                                                    const float* __restrict__ Wm,
                                                    const float* __restrict__ Ws,
                                                    const float* __restrict__ nrm_g,
                                                    float* __restrict__ outm,
                                                    float* __restrict__ outs) {
    __shared__ float hs[16][Hh];  // 8 KB
    __shared__ float nl[16];
    int r0 = blockIdx.x * 16;
    int tid = threadIdx.x;
    if (tid < 16) nl[tid] = nrm_g[r0 + tid];
    __syncthreads();
    for (int idx = tid; idx < 16 * Hh / 4; idx += 128) {
        int row = idx >> 5;  // 32 float4 per row
        float4 v = ((const float4*)agg1)[(size_t)r0 * (Hh / 4) + idx];
        float s = nl[row];
        v.x *= s; v.y *= s; v.z *= s; v.w *= s;
        ((float4*)&hs[0][0])[idx] = v;
    }
    __syncthreads();
    int j = tid & 63, sel = tid >> 6;
    const float* W = sel ? Ws : Wm;
    float* out = sel ? outs : outm;
    float acc[16];
#pragma unroll
    for (int r = 0; r < 16; ++r) acc[r] = 0.0f;
    for (int k = 0; k < Hh; ++k) {
        float w = W[k * DZ + j];
#pragma unroll
        for (int r = 0; r < 16; ++r) acc[r] += hs[r][k] * w;
    }
#pragma unroll
    for (int r = 0; r < 16; ++r) out[(size_t)(r0 + r) * DZ + j] = acc[r] * nl[r];
}

// ---------------- agg2: gather-sum for m and s (wave0 -> m, wave1 -> s) ----------------
__global__ __launch_bounds__(128) void agg2_kernel(const int* __restrict__ csr_src,
                                                   const int* __restrict__ offs,
                                                   const float* __restrict__ tmpm,
                                                   const float* __restrict__ tmps,
                                                   float* __restrict__ aggm,
                                                   float* __restrict__ aggs) {
    __shared__ int sidx[128];
    int node = blockIdx.x;
    int beg = offs[node], end = offs[node + 1];
    int f = threadIdx.x & 63;
    const float* tin = (threadIdx.x >> 6) ? tmps : tmpm;
    float* tout = (threadIdx.x >> 6) ? aggs : aggm;
    float acc = 0.0f;
    for (int e0 = beg; e0 < end; e0 += 128) {
        int n = min(128, end - e0);
        if (threadIdx.x < n) sidx[threadIdx.x] = csr_src[e0 + threadIdx.x];
        __syncthreads();
        for (int t = 0; t < n; ++t)
            acc += tin[(size_t)sidx[t] * DZ + f];
        __syncthreads();
    }
    tout[(size_t)node * DZ + f] = acc;
}

// ---------------- Z = noise * exp(relu(aggs*norm)) + relu(aggm*norm) ----------------
__global__ void z_kernel(const float* __restrict__ aggm, const float* __restrict__ aggs,
                         const float* __restrict__ noise, const float* __restrict__ nrm,
                         float* __restrict__ Z) {
    int i = blockIdx.x * 256 + threadIdx.x;  // < N*DZ
    int node = i >> 6;
    float nr = nrm[node];
    float m = fmaxf(aggm[i] * nr, 0.0f);
    float s = fmaxf(aggs[i] * nr, 0.0f);
    Z[i] = noise[i] * expf(s) + m;
}

// ---------------- adj = Z @ Z^T  [N,N], fp32, 128x128 tile, 8x8 micro ----------------
// LDS layout swizzle: element (row, c) stored at column ((c & ~3) + 4*(row>>3) + (c&3)) & 63.
// Main-loop reads are then conflict-free (A: 4 distinct banks across ty; B: 2-way across tx).
__global__ __launch_bounds__(256) void zzt_kernel(const float* __restrict__ Z,
                                                  float* __restrict__ out) {
    __shared__ float As[128 * 64];  // 32 KB
    __shared__ float Bs[128 * 64];  // 32 KB
    int i0 = blockIdx.y << 7, j0 = blockIdx.x << 7;
    int tid = threadIdx.x;

    for (int idx = tid; idx < 2048; idx += 256) {
        int row = idx >> 4;
        int c4 = idx & 15;                     // float4 slot in row
        int rot = (row >> 3) << 2;             // rotation, multiple of 4
        int cc = ((c4 << 2) + rot) & 63;       // stays 16B-aligned
        float4 a = *(const float4*)(Z + ((size_t)(i0 + row) << 6) + (c4 << 2));
        float4 b = *(const float4*)(Z + ((size_t)(j0 + row) << 6) + (c4 << 2));
        *(float4*)&As[(row << 6) + cc] = a;
        *(float4*)&Bs[(row << 6) + cc] = b;
    }
    __syncthreads();

    int tx = tid & 15, ty = tid >> 4;
    float acc[8][8];
#pragma unroll
    for (int m = 0; m < 8; ++m)
#pragma unroll
        for (int n = 0; n < 8; ++n) acc[m][n] = 0.0f;

    int arot = ty << 2;  // rows ty*8+m all have (row>>3)==ty
    int brot = tx << 2;
    const float* Abase = &As[(ty << 3) << 6];
    const float* Bbase = &Bs[(tx << 3) << 6];

    for (int k4 = 0; k4 < 16; ++k4) {
        int ka = ((k4 << 2) + arot) & 63;
        int kb = ((k4 << 2) + brot) & 63;
        float4 a4[8], b4[8];
#pragma unroll
        for (int m = 0; m < 8; ++m) a4[m] = *(const float4*)&Abase[(m << 6) + ka];
#pragma unroll
        for (int n = 0; n < 8; ++n) b4[n] = *(const float4*)&Bbase[(n << 6) + kb];
#pragma unroll
        for (int m = 0; m < 8; ++m)
#pragma unroll
            for (int n = 0; n < 8; ++n)
                acc[m][n] += a4[m].x * b4[n].x + a4[m].y * b4[n].y +
                             a4[m].z * b4[n].z + a4[m].w * b4[n].w;
    }

#pragma unroll
    for (int m = 0; m < 8; ++m) {
        size_t row = (size_t)(i0 + (ty << 3) + m);
        float4 v0 = {acc[m][0], acc[m][1], acc[m][2], acc[m][3]};
        float4 v1 = {acc[m][4], acc[m][5], acc[m][6], acc[m][7]};
        *(float4*)(out + row * Nn + j0 + (tx << 3)) = v0;
        *(float4*)(out + row * Nn + j0 + (tx << 3) + 4) = v1;
    }
}

extern "C" void kernel_launch(void* const* d_in, const int* in_sizes, int n_in,
                              void* d_out, int out_size, void* d_ws, size_t ws_size,
                              hipStream_t stream) {
    const float* X = (const float*)d_in[0];
    const float* W0 = (const float*)d_in[1];
    const float* Wm = (const float*)d_in[2];
    const float* Ws = (const float*)d_in[3];
    const float* noise = (const float*)d_in[4];
    const int* ei = (const int*)d_in[5];
    const int* srcp = ei;        // edge_index[0]
    const int* dstp = ei + Ee;   // edge_index[1]
    float* out = (float*)d_out;

    float* ws = (float*)d_ws;
    float* deg  = ws;                     // N
    float* agg1 = deg + Nn;               // N*H
    float* aggm = agg1 + (size_t)Nn * Hh; // N*DZ
    float* aggs = aggm + (size_t)Nn * DZ; // N*DZ
    float* nrm  = aggs + (size_t)Nn * DZ; // N
    float* tmp1 = nrm + Nn;               // N*H
    float* tmpm = tmp1 + (size_t)Nn * Hh; // N*DZ
    float* tmps = tmpm + (size_t)Nn * DZ; // N*DZ
    float* Zb   = tmps + (size_t)Nn * DZ; // N*DZ
    int* offs    = (int*)(Zb + (size_t)Nn * DZ); // N+1
    int* cursor  = offs + Nn + 1;                // N
    int* csr_src = cursor + Nn;                  // E

    // only the degree counters need zeroing now (CSR gather writes outputs once)
    hipMemsetAsync(deg, 0, (size_t)Nn * sizeof(float), stream);

    deg_kernel<<<(Ee + 255) / 256, 256, 0, stream>>>(dstp, deg);
    norm_kernel<<<(Nn + 255) / 256, 256, 0, stream>>>(deg, nrm);
    scan_kernel<<<1, 1024, 0, stream>>>(deg, offs, cursor);
    csr_kernel<<<(Ee + 255) / 256, 256, 0, stream>>>(srcp, dstp, cursor, csr_src);
    gemm1_kernel<<<Nn / 16, 128, 0, stream>>>(X, W0, nrm, tmp1);
    agg1_kernel<<<Nn, 128, 0, stream>>>(csr_src, offs, tmp1, agg1);
    gemm2_kernel<<<Nn / 16, 128, 0, stream>>>(agg1, Wm, Ws, nrm, tmpm, tmps);
    agg2_kernel<<<Nn, 128, 0, stream>>>(csr_src, offs, tmpm, tmps, aggm, aggs);
    z_kernel<<<(Nn * DZ) / 256, 256, 0, stream>>>(aggm, aggs, noise, nrm, Zb);
    dim3 g(Nn / 128, Nn / 128);
    zzt_kernel<<<g, 256, 0, stream>>>(Zb, out);
}

// Round 2
// 898.742 us; speedup vs baseline: 1.3082x; 1.0232x over previous
//
#include <hip/hip_runtime.h>
#include <math.h>

#define Nn 12288
#define Ee 393216
#define INF 256
#define Hh 128
#define DZ 64

// ---------------- degree ----------------
__global__ void deg_kernel(const int* __restrict__ dst, float* __restrict__ deg) {
    int i = blockIdx.x * 256 + threadIdx.x;
    if (i < Ee) atomicAdd(&deg[dst[i]], 1.0f);
}

// ---------------- exclusive scan of degrees -> CSR row offsets, + norm (fused) ----------------
__global__ __launch_bounds__(1024) void scan_kernel(const float* __restrict__ deg,
                                                    int* __restrict__ offs,
                                                    int* __restrict__ cursor,
                                                    float* __restrict__ nrm) {
    __shared__ int part[1024];
    int t = threadIdx.x;
    int base = t * 12;
    float dv[12];
    int loc[12];
    int s = 0;
#pragma unroll
    for (int k = 0; k < 12; ++k) {
        dv[k] = deg[base + k];
        loc[k] = s;
        s += (int)dv[k];
    }
    part[t] = s;
    __syncthreads();
    // Hillis-Steele inclusive scan over 1024 partials
    for (int off = 1; off < 1024; off <<= 1) {
        int v = (t >= off) ? part[t - off] : 0;
        __syncthreads();
        part[t] += v;
        __syncthreads();
    }
    int pre = (t == 0) ? 0 : part[t - 1];
#pragma unroll
    for (int k = 0; k < 12; ++k) {
        int o = pre + loc[k];
        offs[base + k] = o;
        cursor[base + k] = o;
        nrm[base + k] = 1.0f / sqrtf(fmaxf(dv[k], 1.0f));
    }
    if (t == 1023) offs[Nn] = part[1023];
}

// ---------------- counting-sort edges by dst: csr_src[p] = src ----------------
__global__ void csr_kernel(const int* __restrict__ src, const int* __restrict__ dst,
                           int* __restrict__ cursor, int* __restrict__ csr_src) {
    int e = blockIdx.x * 256 + threadIdx.x;
    if (e < Ee) {
        int p = atomicAdd(&cursor[dst[e]], 1);
        csr_src[p] = src[e];
    }
}

// ---------------- layer1 GEMM: tmp1 = (X @ W0) * norm  [N,128] ----------------
__global__ __launch_bounds__(128) void gemm1_kernel(const float* __restrict__ X,
                                                    const float* __restrict__ W0,
                                                    const float* __restrict__ nrm,
                                                    float* __restrict__ out) {
    __shared__ float xs[16][INF];  // 16 rows x 256 = 16 KB
    int r0 = blockIdx.x * 16;
    int tid = threadIdx.x;
    const float4* X4 = (const float4*)(X + (size_t)r0 * INF);
    float4* xs4 = (float4*)&xs[0][0];
    for (int idx = tid; idx < 16 * INF / 4; idx += 128) xs4[idx] = X4[idx];
    __syncthreads();
    int j = tid;  // 0..127 output column
    float acc[16];
#pragma unroll
    for (int r = 0; r < 16; ++r) acc[r] = 0.0f;
    for (int k = 0; k < INF; ++k) {
        float w = W0[k * Hh + j];
#pragma unroll
        for (int r = 0; r < 16; ++r) acc[r] = fmaf(xs[r][k], w, acc[r]);
    }
#pragma unroll
    for (int r = 0; r < 16; ++r) out[(size_t)(r0 + r) * Hh + j] = acc[r] * nrm[r0 + r];
}

// ---------------- agg1: gather-sum over CSR (one node per block, 128 feats) ----------------
__global__ __launch_bounds__(128) void agg1_kernel(const int* __restrict__ csr_src,
                                                   const int* __restrict__ offs,
                                                   const float* __restrict__ tmp1,
                                                   float* __restrict__ agg1) {
    __shared__ int sidx[128];
    int node = blockIdx.x;
    int beg = offs[node], end = offs[node + 1];
    int f = threadIdx.x;
    float acc = 0.0f;
    for (int e0 = beg; e0 < end; e0 += 128) {
        int n = min(128, end - e0);
        if (f < n) sidx[f] = csr_src[e0 + f];
        __syncthreads();
        int t = 0;
        // unroll-by-4: 4 independent L2 loads in flight per wait
        for (; t + 4 <= n; t += 4) {
            int s0 = sidx[t], s1 = sidx[t + 1], s2 = sidx[t + 2], s3 = sidx[t + 3];
            float v0 = tmp1[(size_t)s0 * Hh + f];
            float v1 = tmp1[(size_t)s1 * Hh + f];
            float v2 = tmp1[(size_t)s2 * Hh + f];
            float v3 = tmp1[(size_t)s3 * Hh + f];
            acc += (v0 + v1) + (v2 + v3);
        }
        for (; t < n; ++t) acc += tmp1[(size_t)sidx[t] * Hh + f];
        __syncthreads();
    }
    agg1[(size_t)node * Hh + f] = acc;
}

// ---------------- layer2 GEMMs (fused m & s): tmp = ((agg1*norm) @ W) * norm ----------------
__global__ __launch_bounds__(128) void gemm2_kernel(const float* __restrict__ agg1,
                                                    const float* __restrict__ Wm,
                                                    const float* __restrict__ Ws,
                                                    const float* __restrict__ nrm_g,
                                                    float* __restrict__ outm,
                                                    float* __restrict__ outs) {
    __shared__ float hs[16][Hh];  // 8 KB
    __shared__ float nl[16];
    int r0 = blockIdx.x * 16;
    int tid = threadIdx.x;
    if (tid < 16) nl[tid] = nrm_g[r0 + tid];
    __syncthreads();
    for (int idx = tid; idx < 16 * Hh / 4; idx += 128) {
        int row = idx >> 5;  // 32 float4 per row
        float4 v = ((const float4*)agg1)[(size_t)r0 * (Hh / 4) + idx];
        float s = nl[row];
        v.x *= s; v.y *= s; v.z *= s; v.w *= s;
        ((float4*)&hs[0][0])[idx] = v;
    }
    __syncthreads();
    int j = tid & 63, sel = tid >> 6;
    const float* W = sel ? Ws : Wm;
    float* out = sel ? outs : outm;
    float acc[16];
#pragma unroll
    for (int r = 0; r < 16; ++r) acc[r] = 0.0f;
    for (int k = 0; k < Hh; ++k) {
        float w = W[k * DZ + j];
#pragma unroll
        for (int r = 0; r < 16; ++r) acc[r] = fmaf(hs[r][k], w, acc[r]);
    }
#pragma unroll
    for (int r = 0; r < 16; ++r) out[(size_t)(r0 + r) * DZ + j] = acc[r] * nl[r];
}

// ---------------- agg2 + z fused: gather m,s then Z = noise*exp(relu(s*nr)) + relu(m*nr) ----------------
__global__ __launch_bounds__(128) void agg2z_kernel(const int* __restrict__ csr_src,
                                                    const int* __restrict__ offs,
                                                    const float* __restrict__ tmpm,
                                                    const float* __restrict__ tmps,
                                                    const float* __restrict__ nrm,
                                                    const float* __restrict__ noise,
                                                    float* __restrict__ Z) {
    __shared__ int sidx[128];
    __shared__ float sbuf[64];
    int node = blockIdx.x;
    int beg = offs[node], end = offs[node + 1];
    int f = threadIdx.x & 63;
    const float* tin = (threadIdx.x >> 6) ? tmps : tmpm;
    float acc = 0.0f;
    for (int e0 = beg; e0 < end; e0 += 128) {
        int n = min(128, end - e0);
        if (threadIdx.x < n) sidx[threadIdx.x] = csr_src[e0 + threadIdx.x];
        __syncthreads();
        int t = 0;
        for (; t + 4 <= n; t += 4) {
            int s0 = sidx[t], s1 = sidx[t + 1], s2 = sidx[t + 2], s3 = sidx[t + 3];
            float v0 = tin[(size_t)s0 * DZ + f];
            float v1 = tin[(size_t)s1 * DZ + f];
            float v2 = tin[(size_t)s2 * DZ + f];
            float v3 = tin[(size_t)s3 * DZ + f];
            acc += (v0 + v1) + (v2 + v3);
        }
        for (; t < n; ++t) acc += tin[(size_t)sidx[t] * DZ + f];
        __syncthreads();
    }
    // wave1 (s-accumulator) publishes; wave0 computes Z
    if (threadIdx.x >= 64) sbuf[f] = acc;
    __syncthreads();
    if (threadIdx.x < 64) {
        float nr = nrm[node];
        float m = fmaxf(acc * nr, 0.0f);
        float s = fmaxf(sbuf[f] * nr, 0.0f);
        size_t i = (size_t)node * DZ + f;
        Z[i] = fmaf(noise[i], expf(s), m);
    }
}

// ---------------- adj = Z @ Z^T  [N,N], fp32, 128x128 tile, 8x8 micro ----------------
// LDS layout swizzle: element (row, c) stored at column ((c & ~3) + 4*(row>>3) + (c&3)) & 63.
// Main-loop reads are then conflict-free (A: broadcast across 16 lanes; B: 2-way).
// Accumulation via nested fmaf: 4 FMA per 4 MACs (no mul+add split from strict assoc).
__global__ __launch_bounds__(256) void zzt_kernel(const float* __restrict__ Z,
                                                  float* __restrict__ out) {
    __shared__ float As[128 * 64];  // 32 KB
    __shared__ float Bs[128 * 64];  // 32 KB
    int i0 = blockIdx.y << 7, j0 = blockIdx.x << 7;
    int tid = threadIdx.x;

    for (int idx = tid; idx < 2048; idx += 256) {
        int row = idx >> 4;
        int c4 = idx & 15;                     // float4 slot in row
        int rot = (row >> 3) << 2;             // rotation, multiple of 4
        int cc = ((c4 << 2) + rot) & 63;       // stays 16B-aligned
        float4 a = *(const float4*)(Z + ((size_t)(i0 + row) << 6) + (c4 << 2));
        float4 b = *(const float4*)(Z + ((size_t)(j0 + row) << 6) + (c4 << 2));
        *(float4*)&As[(row << 6) + cc] = a;
        *(float4*)&Bs[(row << 6) + cc] = b;
    }
    __syncthreads();

    int tx = tid & 15, ty = tid >> 4;
    float acc[8][8];
#pragma unroll
    for (int m = 0; m < 8; ++m)
#pragma unroll
        for (int n = 0; n < 8; ++n) acc[m][n] = 0.0f;

    int arot = ty << 2;  // rows ty*8+m all have (row>>3)==ty
    int brot = tx << 2;
    const float* Abase = &As[(ty << 3) << 6];
    const float* Bbase = &Bs[(tx << 3) << 6];

#pragma unroll 2
    for (int k4 = 0; k4 < 16; ++k4) {
        int ka = ((k4 << 2) + arot) & 63;
        int kb = ((k4 << 2) + brot) & 63;
        float4 a4[8], b4[8];
#pragma unroll
        for (int m = 0; m < 8; ++m) a4[m] = *(const float4*)&Abase[(m << 6) + ka];
#pragma unroll
        for (int n = 0; n < 8; ++n) b4[n] = *(const float4*)&Bbase[(n << 6) + kb];
#pragma unroll
        for (int m = 0; m < 8; ++m)
#pragma unroll
            for (int n = 0; n < 8; ++n)
                acc[m][n] = fmaf(a4[m].w, b4[n].w,
                            fmaf(a4[m].z, b4[n].z,
                            fmaf(a4[m].y, b4[n].y,
                            fmaf(a4[m].x, b4[n].x, acc[m][n]))));
    }

#pragma unroll
    for (int m = 0; m < 8; ++m) {
        size_t row = (size_t)(i0 + (ty << 3) + m);
        float4 v0 = {acc[m][0], acc[m][1], acc[m][2], acc[m][3]};
        float4 v1 = {acc[m][4], acc[m][5], acc[m][6], acc[m][7]};
        *(float4*)(out + row * Nn + j0 + (tx << 3)) = v0;
        *(float4*)(out + row * Nn + j0 + (tx << 3) + 4) = v1;
    }
}

extern "C" void kernel_launch(void* const* d_in, const int* in_sizes, int n_in,
                              void* d_out, int out_size, void* d_ws, size_t ws_size,
                              hipStream_t stream) {
    const float* X = (const float*)d_in[0];
    const float* W0 = (const float*)d_in[1];
    const float* Wm = (const float*)d_in[2];
    const float* Ws = (const float*)d_in[3];
    const float* noise = (const float*)d_in[4];
    const int* ei = (const int*)d_in[5];
    const int* srcp = ei;        // edge_index[0]
    const int* dstp = ei + Ee;   // edge_index[1]
    float* out = (float*)d_out;

    float* ws = (float*)d_ws;
    float* deg  = ws;                     // N
    float* agg1 = deg + Nn;               // N*H
    float* nrm  = agg1 + (size_t)Nn * Hh; // N
    float* tmp1 = nrm + Nn;               // N*H
    float* tmpm = tmp1 + (size_t)Nn * Hh; // N*DZ
    float* tmps = tmpm + (size_t)Nn * DZ; // N*DZ
    float* Zb   = tmps + (size_t)Nn * DZ; // N*DZ
    int* offs    = (int*)(Zb + (size_t)Nn * DZ); // N+1
    int* cursor  = offs + Nn + 1;                // N
    int* csr_src = cursor + Nn;                  // E

    // only the degree counters need zeroing (CSR gather writes outputs once)
    hipMemsetAsync(deg, 0, (size_t)Nn * sizeof(float), stream);

    deg_kernel<<<(Ee + 255) / 256, 256, 0, stream>>>(dstp, deg);
    scan_kernel<<<1, 1024, 0, stream>>>(deg, offs, cursor, nrm);
    csr_kernel<<<(Ee + 255) / 256, 256, 0, stream>>>(srcp, dstp, cursor, csr_src);
    gemm1_kernel<<<Nn / 16, 128, 0, stream>>>(X, W0, nrm, tmp1);
    agg1_kernel<<<Nn, 128, 0, stream>>>(csr_src, offs, tmp1, agg1);
    gemm2_kernel<<<Nn / 16, 128, 0, stream>>>(agg1, Wm, Ws, nrm, tmpm, tmps);
    agg2z_kernel<<<Nn, 128, 0, stream>>>(csr_src, offs, tmpm, tmps, nrm, noise, Zb);
    dim3 g(Nn / 128, Nn / 128);
    zzt_kernel<<<g, 256, 0, stream>>>(Zb, out);
}

// Round 3
// 832.275 us; speedup vs baseline: 1.4126x; 1.0799x over previous
//
#include <hip/hip_runtime.h>
#include <math.h>

#define Nn 12288
#define Ee 393216
#define INF 256
#define Hh 128
#define DZ 64

typedef short v8s __attribute__((ext_vector_type(8)));   // 8 bf16 in 4 VGPRs
typedef float v4f __attribute__((ext_vector_type(4)));   // mfma accumulator

// bf16 round-to-nearest-even helpers
__device__ __forceinline__ unsigned short f2bf_rn(float f) {
    unsigned int u = __float_as_uint(f);
    unsigned int r = (u + 0x7FFFu + ((u >> 16) & 1u)) >> 16;
    return (unsigned short)r;
}
__device__ __forceinline__ float bf2f(unsigned short h) {
    return __uint_as_float((unsigned int)h << 16);
}

// ---------------- degree ----------------
__global__ void deg_kernel(const int* __restrict__ dst, float* __restrict__ deg) {
    int i = blockIdx.x * 256 + threadIdx.x;
    if (i < Ee) atomicAdd(&deg[dst[i]], 1.0f);
}

// ---------------- exclusive scan of degrees -> CSR row offsets, + norm (fused) ----------------
__global__ __launch_bounds__(1024) void scan_kernel(const float* __restrict__ deg,
                                                    int* __restrict__ offs,
                                                    int* __restrict__ cursor,
                                                    float* __restrict__ nrm) {
    __shared__ int part[1024];
    int t = threadIdx.x;
    int base = t * 12;
    float dv[12];
    int loc[12];
    int s = 0;
#pragma unroll
    for (int k = 0; k < 12; ++k) {
        dv[k] = deg[base + k];
        loc[k] = s;
        s += (int)dv[k];
    }
    part[t] = s;
    __syncthreads();
    // Hillis-Steele inclusive scan over 1024 partials
    for (int off = 1; off < 1024; off <<= 1) {
        int v = (t >= off) ? part[t - off] : 0;
        __syncthreads();
        part[t] += v;
        __syncthreads();
    }
    int pre = (t == 0) ? 0 : part[t - 1];
#pragma unroll
    for (int k = 0; k < 12; ++k) {
        int o = pre + loc[k];
        offs[base + k] = o;
        cursor[base + k] = o;
        nrm[base + k] = 1.0f / sqrtf(fmaxf(dv[k], 1.0f));
    }
    if (t == 1023) offs[Nn] = part[1023];
}

// ---------------- counting-sort edges by dst: csr_src[p] = src ----------------
__global__ void csr_kernel(const int* __restrict__ src, const int* __restrict__ dst,
                           int* __restrict__ cursor, int* __restrict__ csr_src) {
    int e = blockIdx.x * 256 + threadIdx.x;
    if (e < Ee) {
        int p = atomicAdd(&cursor[dst[e]], 1);
        csr_src[p] = src[e];
    }
}

// ---------------- layer1 GEMM: tmp1 = (X @ W0) * norm  [N,128] ----------------
__global__ __launch_bounds__(128) void gemm1_kernel(const float* __restrict__ X,
                                                    const float* __restrict__ W0,
                                                    const float* __restrict__ nrm,
                                                    float* __restrict__ out) {
    __shared__ float xs[16][INF];  // 16 rows x 256 = 16 KB
    int r0 = blockIdx.x * 16;
    int tid = threadIdx.x;
    const float4* X4 = (const float4*)(X + (size_t)r0 * INF);
    float4* xs4 = (float4*)&xs[0][0];
    for (int idx = tid; idx < 16 * INF / 4; idx += 128) xs4[idx] = X4[idx];
    __syncthreads();
    int j = tid;  // 0..127 output column
    float acc[16];
#pragma unroll
    for (int r = 0; r < 16; ++r) acc[r] = 0.0f;
    for (int k = 0; k < INF; ++k) {
        float w = W0[k * Hh + j];
#pragma unroll
        for (int r = 0; r < 16; ++r) acc[r] = fmaf(xs[r][k], w, acc[r]);
    }
#pragma unroll
    for (int r = 0; r < 16; ++r) out[(size_t)(r0 + r) * Hh + j] = acc[r] * nrm[r0 + r];
}

// ---------------- agg1: gather-sum over CSR (one node per block, 128 feats) ----------------
__global__ __launch_bounds__(128) void agg1_kernel(const int* __restrict__ csr_src,
                                                   const int* __restrict__ offs,
                                                   const float* __restrict__ tmp1,
                                                   float* __restrict__ agg1) {
    __shared__ int sidx[128];
    int node = blockIdx.x;
    int beg = offs[node], end = offs[node + 1];
    int f = threadIdx.x;
    float acc = 0.0f;
    for (int e0 = beg; e0 < end; e0 += 128) {
        int n = min(128, end - e0);
        if (f < n) sidx[f] = csr_src[e0 + f];
        __syncthreads();
        int t = 0;
        // unroll-by-4: 4 independent L2 loads in flight per wait
        for (; t + 4 <= n; t += 4) {
            int s0 = sidx[t], s1 = sidx[t + 1], s2 = sidx[t + 2], s3 = sidx[t + 3];
            float v0 = tmp1[(size_t)s0 * Hh + f];
            float v1 = tmp1[(size_t)s1 * Hh + f];
            float v2 = tmp1[(size_t)s2 * Hh + f];
            float v3 = tmp1[(size_t)s3 * Hh + f];
            acc += (v0 + v1) + (v2 + v3);
        }
        for (; t < n; ++t) acc += tmp1[(size_t)sidx[t] * Hh + f];
        __syncthreads();
    }
    agg1[(size_t)node * Hh + f] = acc;
}

// ---------------- layer2 GEMMs (fused m & s): tmp = ((agg1*norm) @ W) * norm ----------------
__global__ __launch_bounds__(128) void gemm2_kernel(const float* __restrict__ agg1,
                                                    const float* __restrict__ Wm,
                                                    const float* __restrict__ Ws,
                                                    const float* __restrict__ nrm_g,
                                                    float* __restrict__ outm,
                                                    float* __restrict__ outs) {
    __shared__ float hs[16][Hh];  // 8 KB
    __shared__ float nl[16];
    int r0 = blockIdx.x * 16;
    int tid = threadIdx.x;
    if (tid < 16) nl[tid] = nrm_g[r0 + tid];
    __syncthreads();
    for (int idx = tid; idx < 16 * Hh / 4; idx += 128) {
        int row = idx >> 5;  // 32 float4 per row
        float4 v = ((const float4*)agg1)[(size_t)r0 * (Hh / 4) + idx];
        float s = nl[row];
        v.x *= s; v.y *= s; v.z *= s; v.w *= s;
        ((float4*)&hs[0][0])[idx] = v;
    }
    __syncthreads();
    int j = tid & 63, sel = tid >> 6;
    const float* W = sel ? Ws : Wm;
    float* out = sel ? outs : outm;
    float acc[16];
#pragma unroll
    for (int r = 0; r < 16; ++r) acc[r] = 0.0f;
    for (int k = 0; k < Hh; ++k) {
        float w = W[k * DZ + j];
#pragma unroll
        for (int r = 0; r < 16; ++r) acc[r] = fmaf(hs[r][k], w, acc[r]);
    }
#pragma unroll
    for (int r = 0; r < 16; ++r) out[(size_t)(r0 + r) * DZ + j] = acc[r] * nl[r];
}

// ---------------- agg2 + z fused: gather m,s; Z = noise*exp(relu(s*nr)) + relu(m*nr);
//                  emit split-bf16 Zhi/Zlo for the MFMA ZZ^T ----------------
__global__ __launch_bounds__(128) void agg2z_kernel(const int* __restrict__ csr_src,
                                                    const int* __restrict__ offs,
                                                    const float* __restrict__ tmpm,
                                                    const float* __restrict__ tmps,
                                                    const float* __restrict__ nrm,
                                                    const float* __restrict__ noise,
                                                    unsigned short* __restrict__ Zhi,
                                                    unsigned short* __restrict__ Zlo) {
    __shared__ int sidx[128];
    __shared__ float sbuf[64];
    int node = blockIdx.x;
    int beg = offs[node], end = offs[node + 1];
    int f = threadIdx.x & 63;
    const float* tin = (threadIdx.x >> 6) ? tmps : tmpm;
    float acc = 0.0f;
    for (int e0 = beg; e0 < end; e0 += 128) {
        int n = min(128, end - e0);
        if (threadIdx.x < n) sidx[threadIdx.x] = csr_src[e0 + threadIdx.x];
        __syncthreads();
        int t = 0;
        for (; t + 4 <= n; t += 4) {
            int s0 = sidx[t], s1 = sidx[t + 1], s2 = sidx[t + 2], s3 = sidx[t + 3];
            float v0 = tin[(size_t)s0 * DZ + f];
            float v1 = tin[(size_t)s1 * DZ + f];
            float v2 = tin[(size_t)s2 * DZ + f];
            float v3 = tin[(size_t)s3 * DZ + f];
            acc += (v0 + v1) + (v2 + v3);
        }
        for (; t < n; ++t) acc += tin[(size_t)sidx[t] * DZ + f];
        __syncthreads();
    }
    // wave1 (s-accumulator) publishes; wave0 computes Z and splits to bf16 hi/lo
    if (threadIdx.x >= 64) sbuf[f] = acc;
    __syncthreads();
    if (threadIdx.x < 64) {
        float nr = nrm[node];
        float m = fmaxf(acc * nr, 0.0f);
        float s = fmaxf(sbuf[f] * nr, 0.0f);
        size_t i = (size_t)node * DZ + f;
        float z = fmaf(noise[i], expf(s), m);
        unsigned short h = f2bf_rn(z);
        Zhi[i] = h;
        Zlo[i] = f2bf_rn(z - bf2f(h));
    }
}

// ---------------- adj = Z @ Z^T via split-bf16 MFMA ----------------
// z = hi + lo (bf16 each); z_i*z_j ~= hi*hi + hi*lo + lo*hi  (lo*lo ~ 2^-18, dropped).
// mfma_f32_16x16x32_bf16, A-frag == B-frag load pattern (C = Z Z^T symmetry):
//   lane l: row/col = base + (l&15), k = kh*32 + (l>>4)*8 .. +8 (16B contiguous).
// 128x128 tile, 4 waves; wave w: rows w*32 + {0,16}, all 8 col-groups. No LDS, no barriers.
__global__ __launch_bounds__(256) void zzt_kernel(const unsigned short* __restrict__ Zhi,
                                                  const unsigned short* __restrict__ Zlo,
                                                  float* __restrict__ out) {
    int i0 = blockIdx.y << 7, j0 = blockIdx.x << 7;
    int tid = threadIdx.x;
    int w = tid >> 6, lane = tid & 63;
    int rsel = lane & 15;
    int kgrp = (lane >> 4) << 3;  // 0,8,16,24

    v4f acc[2][8];
#pragma unroll
    for (int mi = 0; mi < 2; ++mi)
#pragma unroll
        for (int nj = 0; nj < 8; ++nj) acc[mi][nj] = (v4f){0.f, 0.f, 0.f, 0.f};

    int arow = i0 + (w << 5) + rsel;  // + mi*16
    int brow = j0 + rsel;             // + nj*16

#pragma unroll
    for (int kh = 0; kh < 2; ++kh) {
        int koff = (kh << 5) + kgrp;
        v8s ahi[2], alo[2], bhi[8], blo[8];
#pragma unroll
        for (int mi = 0; mi < 2; ++mi) {
            size_t p = (size_t)(arow + (mi << 4)) * DZ + koff;
            ahi[mi] = *reinterpret_cast<const v8s*>(Zhi + p);
            alo[mi] = *reinterpret_cast<const v8s*>(Zlo + p);
        }
#pragma unroll
        for (int nj = 0; nj < 8; ++nj) {
            size_t p = (size_t)(brow + (nj << 4)) * DZ + koff;
            bhi[nj] = *reinterpret_cast<const v8s*>(Zhi + p);
            blo[nj] = *reinterpret_cast<const v8s*>(Zlo + p);
        }
#pragma unroll
        for (int mi = 0; mi < 2; ++mi)
#pragma unroll
            for (int nj = 0; nj < 8; ++nj) {
                acc[mi][nj] = __builtin_amdgcn_mfma_f32_16x16x32_bf16(alo[mi], bhi[nj], acc[mi][nj], 0, 0, 0);
                acc[mi][nj] = __builtin_amdgcn_mfma_f32_16x16x32_bf16(ahi[mi], blo[nj], acc[mi][nj], 0, 0, 0);
                acc[mi][nj] = __builtin_amdgcn_mfma_f32_16x16x32_bf16(ahi[mi], bhi[nj], acc[mi][nj], 0, 0, 0);
            }
    }

    // C/D layout (verified m89/m91): col = lane&15, row = (lane>>4)*4 + reg
    int rowb = (lane >> 4) << 2;
    int colb = lane & 15;
#pragma unroll
    for (int mi = 0; mi < 2; ++mi) {
        int rbase = i0 + (w << 5) + (mi << 4) + rowb;
#pragma unroll
        for (int r = 0; r < 4; ++r) {
            size_t rowoff = (size_t)(rbase + r) * Nn + j0 + colb;
#pragma unroll
            for (int nj = 0; nj < 8; ++nj)
                out[rowoff + (nj << 4)] = acc[mi][nj][r];
        }
    }
}

extern "C" void kernel_launch(void* const* d_in, const int* in_sizes, int n_in,
                              void* d_out, int out_size, void* d_ws, size_t ws_size,
                              hipStream_t stream) {
    const float* X = (const float*)d_in[0];
    const float* W0 = (const float*)d_in[1];
    const float* Wm = (const float*)d_in[2];
    const float* Ws = (const float*)d_in[3];
    const float* noise = (const float*)d_in[4];
    const int* ei = (const int*)d_in[5];
    const int* srcp = ei;        // edge_index[0]
    const int* dstp = ei + Ee;   // edge_index[1]
    float* out = (float*)d_out;

    float* ws = (float*)d_ws;
    float* deg  = ws;                     // N
    float* agg1 = deg + Nn;               // N*H
    float* nrm  = agg1 + (size_t)Nn * Hh; // N
    float* tmp1 = nrm + Nn;               // N*H
    float* tmpm = tmp1 + (size_t)Nn * Hh; // N*DZ
    float* tmps = tmpm + (size_t)Nn * DZ; // N*DZ
    unsigned short* Zhi = (unsigned short*)(tmps + (size_t)Nn * DZ); // N*DZ bf16
    unsigned short* Zlo = Zhi + (size_t)Nn * DZ;                     // N*DZ bf16
    int* offs    = (int*)(Zlo + (size_t)Nn * DZ); // N+1
    int* cursor  = offs + Nn + 1;                 // N
    int* csr_src = cursor + Nn;                   // E

    // only the degree counters need zeroing (CSR gather writes outputs once)
    hipMemsetAsync(deg, 0, (size_t)Nn * sizeof(float), stream);

    deg_kernel<<<(Ee + 255) / 256, 256, 0, stream>>>(dstp, deg);
    scan_kernel<<<1, 1024, 0, stream>>>(deg, offs, cursor, nrm);
    csr_kernel<<<(Ee + 255) / 256, 256, 0, stream>>>(srcp, dstp, cursor, csr_src);
    gemm1_kernel<<<Nn / 16, 128, 0, stream>>>(X, W0, nrm, tmp1);
    agg1_kernel<<<Nn, 128, 0, stream>>>(csr_src, offs, tmp1, agg1);
    gemm2_kernel<<<Nn / 16, 128, 0, stream>>>(agg1, Wm, Ws, nrm, tmpm, tmps);
    agg2z_kernel<<<Nn, 128, 0, stream>>>(csr_src, offs, tmpm, tmps, nrm, noise, Zhi, Zlo);
    dim3 g(Nn / 128, Nn / 128);
    zzt_kernel<<<g, 256, 0, stream>>>(Zhi, Zlo, out);
}